// Round 7
// baseline (186.747 us; speedup 1.0000x reference)
//
#include <hip/hip_runtime.h>
#include <cmath>

typedef unsigned int u32;
typedef unsigned long long u64;
typedef u32 v4u __attribute__((ext_vector_type(4)));   // native vec for NT ops

// 64 theta values = powf(10000f, -i/64) computed on HOST with glibc powf
// (same implementation the XLA constant-folder used), passed via kernarg.
struct ThetaArr { float t[64]; };

// glibc sysdeps/ieee754/flt-32 __inv_pio4 table (192-bit 4/pi, byte-sliding).
__device__ const u32 g_inv_pio4[24] = {
  0x000000a2u, 0x0000a2f9u, 0x00a2f983u, 0xa2f9836eu,
  0xf9836e4eu, 0x836e4e44u, 0x6e4e4415u, 0x4e441529u,
  0x441529fcu, 0x1529fc27u, 0x29fc2757u, 0xfc2757d1u,
  0x2757d1f5u, 0x57d1f534u, 0xd1f534ddu, 0xf534ddc0u,
  0x34ddc0dbu, 0xddc0db62u, 0xc0db6295u, 0xdb629599u,
  0x6295993cu, 0x95993c43u, 0x993c4390u, 0x3c439041u
};

__device__ __forceinline__ double sin_poly_d(double x, double x2) {
#pragma clang fp contract(off)
  const double s1 = -0x1.555545995a603p-3;
  const double s2 =  0x1.1107605230bc4p-7;
  const double s3 = -0x1.994eb3774cf24p-13;
  double x3  = x * x2;
  double s1v = __builtin_fma(x2, s3, s2);
  double x7  = x3 * x2;
  double s   = __builtin_fma(x3, s1, x);
  return __builtin_fma(x7, s1v, s);
}

__device__ __forceinline__ double cos_poly_d(double x2) {
#pragma clang fp contract(off)
  const double c0 =  1.0;
  const double c1 = -0x1.ffffffd0c621cp-2;
  const double c2 =  0x1.55553e1068f19p-5;
  const double c3 = -0x1.6c087e89a359dp-10;
  const double c4 =  0x1.99343027bf8c3p-16;
  double x4  = x2 * x2;
  double c2v = __builtin_fma(x2, c4, c3);
  double c1v = __builtin_fma(x2, c1, c0);
  double x6  = x4 * x2;
  double cv  = __builtin_fma(x4, c2, c1v);
  return __builtin_fma(x6, c2v, cv);
}

// Bit-exact port of glibc (>=2.28) __sinf/__cosf for 0 <= y < 2^12.
// Verified absmax == 0.0 on hardware (Rounds 2-6).
__device__ __forceinline__ void sincosf_glibc(float y, float& sf, float& cf) {
#pragma clang fp contract(off)
  const double hpi_inv = 0x1.45F306DC9C883p+23;
  const double hpi     = 0x1.921FB54442D18p0;
  const double pi63    = 0x1.921FB54442D18p-62;
  u32 xi = __float_as_uint(y);
  u32 abstop = (xi >> 20) & 0x7ffu;
  double x = (double)y;
  if (abstop < 0x398u) { sf = y; cf = 1.0f; return; }
  if (abstop < 0x3f4u) {
    double x2 = x * x;
    sf = (float)sin_poly_d(x, x2);
    cf = (float)cos_poly_d(x2);
    return;
  }
  int n;
  double xr;
  if (abstop < 0x42fu) {                         // reduce_fast
    double r = x * hpi_inv;
    n = (((int)r) + 0x800000) >> 24;
    xr = __builtin_fma(-(double)n, hpi, x);
  } else {                                       // reduce_large
    int idx = (xi >> 26) & 15;
    int sh  = (xi >> 23) & 7;
    u32 xm  = ((xi & 0xffffffu) | 0x800000u) << sh;
    u64 res0 = (u64)(u32)(xm * g_inv_pio4[idx]);
    u64 res1 = (u64)xm * (u64)g_inv_pio4[idx + 4];
    u64 res2 = (u64)xm * (u64)g_inv_pio4[idx + 8];
    res0 = ((res2 >> 32) | (res0 << 32)) + res1;
    u64 nn = (res0 + (1ull << 61)) >> 62;
    res0 -= nn << 62;
    double xd = (double)(long long)res0;
    xr = xd * pi63;
    n = (int)nn;
  }
  double x2 = xr * xr;
  double sp = sin_poly_d(xr, x2);
  double cp = cos_poly_d(x2);
  float spf = (float)sp, cpf = (float)cp;
  bool flip = (n & 2) != 0;
  float sres, cres;
  if (n & 1) {
    sres = flip ? -cpf : cpf;
    cres = flip ?  spf : -spf;
  } else {
    sres = flip ? -spf : spf;
    cres = flip ? -cpf : cpf;
  }
  sf = sres; cf = cres;
}

// Wave-autonomous + software-pipelined + full-machine TLP:
// 2048 blocks x 4 waves = 8192 waves (8 waves/SIMD at 64 VGPR, pinned by
// __launch_bounds__(256,8)); each wave handles 2 rows (prologue + one
// pipelined iteration). Next-row loads issue before the sincos/encode/store
// of the current row; NT stores keep the output stream out of L3 so the
// input stream retains residency.
__global__ __launch_bounds__(256, 8) void spike_rope_kernel(
    const float* __restrict__ xin, const int* __restrict__ position,
    float* __restrict__ outp, ThetaArr th, int batch)
{
#pragma clang fp contract(off)
  const int lane = (int)(threadIdx.x & 63u);
  const int wid  = (int)(threadIdx.x >> 6);
  const int nw   = (int)gridDim.x * 4;     // total waves
  int row = (int)blockIdx.x * 4 + wid;
  if (row >= batch) return;

  const int grp = lane >> 3;        // element sub-index within chunk (0..7)
  const int sub = lane & 7;         // 4-pulse slot within element (0..7)
  const int j0  = sub << 2;
  const int shN = 28 - j0;          // nibble placement shift (decode)
  const int sh0 = 31 - j0;          // first bit shift (encode)
  const int dsrc = sub << 3;        // decode route source lane

  const v4u* gx = (const v4u*)xin;
  v4u* gy = (v4u*)outp;

  // ---- prologue: load first row (coalesced 1KiB/instr) ----
  v4u v[16];
  {
    const v4u* rp = gx + (size_t)row * 1024;
#pragma unroll
    for (int s = 0; s < 16; ++s) v[s] = rp[s * 64 + lane];
  }

  for (;;) {
    // ---- decode current row from v[] (in-register transpose) ----
    u32 x1w = 0, x2w = 0;
#pragma unroll
    for (int s = 0; s < 16; ++s) {
      v4u q = v[s];
      u32 nib = (((q.x >> 23) & 1u) << 3) | (((q.y >> 23) & 1u) << 2) |
                (((q.z >> 23) & 1u) << 1) | ((q.w >> 23) & 1u);
      u32 part = nib << shN;
      part |= (u32)__shfl_xor((int)part, 1, 64);
      part |= (u32)__shfl_xor((int)part, 2, 64);
      part |= (u32)__shfl_xor((int)part, 4, 64);
      u32 full = (u32)__shfl((int)part, dsrc, 64);
      if (s < 8) { if (grp == s)     x1w = full; }
      else       { if (grp == s - 8) x2w = full; }
    }

    // ---- prefetch next row into v[] (overlaps sincos + stores) ----
    const int nrow = row + nw;
    const bool have_next = (nrow < batch);
    if (have_next) {
      const v4u* rp = gx + (size_t)nrow * 1024;
#pragma unroll
      for (int s = 0; s < 16; ++s) v[s] = rp[s * 64 + lane];
    }

    // ---- bit-exact fp32 RoPE (verified path, unchanged) ----
    float pf = (float)position[row];   // exact int->f32
    float ang = pf * th.t[lane];       // single f32 mul
    float sv, cv;
    sincosf_glibc(ang, sv, cv);
    float x1 = __uint_as_float(x1w);
    float x2 = __uint_as_float(x2w);
    // reference: r1 = x1*cos + (-x2)*sin ; r2 = x2*cos + x1*sin (NO fma)
    float r1 = (x1 * cv) + ((-x2) * sv);
    float r2 = (x2 * cv) + (x1 * sv);
    u32 o1 = __float_as_uint(r1);
    u32 o2 = __float_as_uint(r2);

    // ---- in-register transpose + encode + nontemporal store ----
    v4u* orow = gy + (size_t)row * 1024;
#pragma unroll
    for (int s = 0; s < 16; ++s) {
      int sl = ((s & 7) << 3) + grp;           // source lane holding element
      u32 ow = (u32)__shfl((int)(s < 8 ? o1 : o2), sl, 64);
      v4u w;
      w.x = ((ow >> sh0) & 1u)       ? 0x3f800000u : 0u;
      w.y = ((ow >> (sh0 - 1)) & 1u) ? 0x3f800000u : 0u;
      w.z = ((ow >> (sh0 - 2)) & 1u) ? 0x3f800000u : 0u;
      w.w = ((ow >> (sh0 - 3)) & 1u) ? 0x3f800000u : 0u;
      __builtin_nontemporal_store(w, &orow[s * 64 + lane]);
    }

    if (!have_next) break;
    row = nrow;
  }
}

extern "C" void kernel_launch(void* const* d_in, const int* in_sizes, int n_in,
                              void* d_out, int out_size, void* d_ws, size_t ws_size,
                              hipStream_t stream) {
  const float* x = (const float*)d_in[0];
  const int* position = (const int*)d_in[1];
  float* out = (float*)d_out;
  int batch = in_sizes[1];

  // theta[i] = powf(10000f, -2f*i/128f) via the runtime glibc powf.
  // volatile fn-pointer defeats LLVM constant folding.
  ThetaArr th;
  float (*volatile pfn)(float, float) = &powf;
  for (int i = 0; i < 64; ++i) {
    float e = (-2.0f * (float)i) / 128.0f;
    th.t[i] = pfn(10000.0f, e);
  }

  // 2048 blocks x 4 waves = 8192 waves -> 32 waves/CU (8/SIMD at 64 VGPR);
  // each wave handles 2 rows: prologue + one fully-pipelined iteration.
  int blocks = (batch + 7) / 8;    // 2 rows per wave
  if (blocks > 2048) blocks = 2048;
  spike_rope_kernel<<<blocks, 256, 0, stream>>>(x, position, out, th, batch);
}

// Round 8
// 85.226 us; speedup vs baseline: 2.1912x; 2.1912x over previous
//
#include <hip/hip_runtime.h>
#include <cmath>

typedef unsigned int u32;
typedef unsigned long long u64;
typedef u32 v4u __attribute__((ext_vector_type(4)));   // native vec for NT ops

// 64 theta values = powf(10000f, -i/64) computed on HOST with glibc powf
// (same implementation the XLA constant-folder used), passed via kernarg.
struct ThetaArr { float t[64]; };

// glibc sysdeps/ieee754/flt-32 __inv_pio4 table (192-bit 4/pi, byte-sliding).
__device__ const u32 g_inv_pio4[24] = {
  0x000000a2u, 0x0000a2f9u, 0x00a2f983u, 0xa2f9836eu,
  0xf9836e4eu, 0x836e4e44u, 0x6e4e4415u, 0x4e441529u,
  0x441529fcu, 0x1529fc27u, 0x29fc2757u, 0xfc2757d1u,
  0x2757d1f5u, 0x57d1f534u, 0xd1f534ddu, 0xf534ddc0u,
  0x34ddc0dbu, 0xddc0db62u, 0xc0db6295u, 0xdb629599u,
  0x6295993cu, 0x95993c43u, 0x993c4390u, 0x3c439041u
};

__device__ __forceinline__ double sin_poly_d(double x, double x2) {
#pragma clang fp contract(off)
  const double s1 = -0x1.555545995a603p-3;
  const double s2 =  0x1.1107605230bc4p-7;
  const double s3 = -0x1.994eb3774cf24p-13;
  double x3  = x * x2;
  double s1v = __builtin_fma(x2, s3, s2);
  double x7  = x3 * x2;
  double s   = __builtin_fma(x3, s1, x);
  return __builtin_fma(x7, s1v, s);
}

__device__ __forceinline__ double cos_poly_d(double x2) {
#pragma clang fp contract(off)
  const double c0 =  1.0;
  const double c1 = -0x1.ffffffd0c621cp-2;
  const double c2 =  0x1.55553e1068f19p-5;
  const double c3 = -0x1.6c087e89a359dp-10;
  const double c4 =  0x1.99343027bf8c3p-16;
  double x4  = x2 * x2;
  double c2v = __builtin_fma(x2, c4, c3);
  double c1v = __builtin_fma(x2, c1, c0);
  double x6  = x4 * x2;
  double cv  = __builtin_fma(x4, c2, c1v);
  return __builtin_fma(x6, c2v, cv);
}

// Bit-exact port of glibc (>=2.28) __sinf/__cosf for 0 <= y < 2^12.
// Verified absmax == 0.0 on hardware (Rounds 2-7).
__device__ __forceinline__ void sincosf_glibc(float y, float& sf, float& cf) {
#pragma clang fp contract(off)
  const double hpi_inv = 0x1.45F306DC9C883p+23;
  const double hpi     = 0x1.921FB54442D18p0;
  const double pi63    = 0x1.921FB54442D18p-62;
  u32 xi = __float_as_uint(y);
  u32 abstop = (xi >> 20) & 0x7ffu;
  double x = (double)y;
  if (abstop < 0x398u) { sf = y; cf = 1.0f; return; }
  if (abstop < 0x3f4u) {
    double x2 = x * x;
    sf = (float)sin_poly_d(x, x2);
    cf = (float)cos_poly_d(x2);
    return;
  }
  int n;
  double xr;
  if (abstop < 0x42fu) {                         // reduce_fast
    double r = x * hpi_inv;
    n = (((int)r) + 0x800000) >> 24;
    xr = __builtin_fma(-(double)n, hpi, x);
  } else {                                       // reduce_large
    int idx = (xi >> 26) & 15;
    int sh  = (xi >> 23) & 7;
    u32 xm  = ((xi & 0xffffffu) | 0x800000u) << sh;
    u64 res0 = (u64)(u32)(xm * g_inv_pio4[idx]);
    u64 res1 = (u64)xm * (u64)g_inv_pio4[idx + 4];
    u64 res2 = (u64)xm * (u64)g_inv_pio4[idx + 8];
    res0 = ((res2 >> 32) | (res0 << 32)) + res1;
    u64 nn = (res0 + (1ull << 61)) >> 62;
    res0 -= nn << 62;
    double xd = (double)(long long)res0;
    xr = xd * pi63;
    n = (int)nn;
  }
  double x2 = xr * xr;
  double sp = sin_poly_d(xr, x2);
  double cp = cos_poly_d(x2);
  float spf = (float)sp, cpf = (float)cp;
  bool flip = (n & 2) != 0;
  float sres, cres;
  if (n & 1) {
    sres = flip ? -cpf : cpf;
    cres = flip ?  spf : -spf;
  } else {
    sres = flip ? -spf : spf;
    cres = flip ? -cpf : cpf;
  }
  sf = sres; cf = cres;
}

// Wave-autonomous + software-pipelined. __launch_bounds__(256,4) is the
// spill-free point: compiler allocates exactly 64 VGPR (v[16] buffer), which
// the HARDWARE still schedules at 8 waves/SIMD (occupancy steps at 64 VGPR).
// (256,8) forced 32 VGPR and spilled the row buffer to scratch: 84->187us.
// Grid = 2048 blocks -> 8 blocks/CU -> up to 32 waves/CU resident; each wave
// handles 2 rows (prologue + one pipelined iteration).
__global__ __launch_bounds__(256, 4) void spike_rope_kernel(
    const float* __restrict__ xin, const int* __restrict__ position,
    float* __restrict__ outp, ThetaArr th, int batch)
{
#pragma clang fp contract(off)
  const int lane = (int)(threadIdx.x & 63u);
  const int wid  = (int)(threadIdx.x >> 6);
  const int nw   = (int)gridDim.x * 4;     // total waves
  int row = (int)blockIdx.x * 4 + wid;
  if (row >= batch) return;

  const int grp = lane >> 3;        // element sub-index within chunk (0..7)
  const int sub = lane & 7;         // 4-pulse slot within element (0..7)
  const int j0  = sub << 2;
  const int shN = 28 - j0;          // nibble placement shift (decode)
  const int sh0 = 31 - j0;          // first bit shift (encode)
  const int dsrc = sub << 3;        // decode route source lane

  const v4u* gx = (const v4u*)xin;
  v4u* gy = (v4u*)outp;

  // ---- prologue: load first row (coalesced 1KiB/instr) ----
  v4u v[16];
  {
    const v4u* rp = gx + (size_t)row * 1024;
#pragma unroll
    for (int s = 0; s < 16; ++s) v[s] = rp[s * 64 + lane];
  }

  for (;;) {
    // ---- decode current row from v[] (in-register transpose) ----
    u32 x1w = 0, x2w = 0;
#pragma unroll
    for (int s = 0; s < 16; ++s) {
      v4u q = v[s];
      u32 nib = (((q.x >> 23) & 1u) << 3) | (((q.y >> 23) & 1u) << 2) |
                (((q.z >> 23) & 1u) << 1) | ((q.w >> 23) & 1u);
      u32 part = nib << shN;
      part |= (u32)__shfl_xor((int)part, 1, 64);
      part |= (u32)__shfl_xor((int)part, 2, 64);
      part |= (u32)__shfl_xor((int)part, 4, 64);
      u32 full = (u32)__shfl((int)part, dsrc, 64);
      if (s < 8) { if (grp == s)     x1w = full; }
      else       { if (grp == s - 8) x2w = full; }
    }

    // ---- prefetch next row into v[] (overlaps sincos + stores) ----
    const int nrow = row + nw;
    const bool have_next = (nrow < batch);
    if (have_next) {
      const v4u* rp = gx + (size_t)nrow * 1024;
#pragma unroll
      for (int s = 0; s < 16; ++s) v[s] = rp[s * 64 + lane];
    }

    // ---- bit-exact fp32 RoPE (verified path, unchanged) ----
    float pf = (float)position[row];   // exact int->f32
    float ang = pf * th.t[lane];       // single f32 mul
    float sv, cv;
    sincosf_glibc(ang, sv, cv);
    float x1 = __uint_as_float(x1w);
    float x2 = __uint_as_float(x2w);
    // reference: r1 = x1*cos + (-x2)*sin ; r2 = x2*cos + x1*sin (NO fma)
    float r1 = (x1 * cv) + ((-x2) * sv);
    float r2 = (x2 * cv) + (x1 * sv);
    u32 o1 = __float_as_uint(r1);
    u32 o2 = __float_as_uint(r2);

    // ---- in-register transpose + encode + nontemporal store ----
    v4u* orow = gy + (size_t)row * 1024;
#pragma unroll
    for (int s = 0; s < 16; ++s) {
      int sl = ((s & 7) << 3) + grp;           // source lane holding element
      u32 ow = (u32)__shfl((int)(s < 8 ? o1 : o2), sl, 64);
      v4u w;
      w.x = ((ow >> sh0) & 1u)       ? 0x3f800000u : 0u;
      w.y = ((ow >> (sh0 - 1)) & 1u) ? 0x3f800000u : 0u;
      w.z = ((ow >> (sh0 - 2)) & 1u) ? 0x3f800000u : 0u;
      w.w = ((ow >> (sh0 - 3)) & 1u) ? 0x3f800000u : 0u;
      __builtin_nontemporal_store(w, &orow[s * 64 + lane]);
    }

    if (!have_next) break;
    row = nrow;
  }
}

extern "C" void kernel_launch(void* const* d_in, const int* in_sizes, int n_in,
                              void* d_out, int out_size, void* d_ws, size_t ws_size,
                              hipStream_t stream) {
  const float* x = (const float*)d_in[0];
  const int* position = (const int*)d_in[1];
  float* out = (float*)d_out;
  int batch = in_sizes[1];

  // theta[i] = powf(10000f, -2f*i/128f) via the runtime glibc powf.
  // volatile fn-pointer defeats LLVM constant folding.
  ThetaArr th;
  float (*volatile pfn)(float, float) = &powf;
  for (int i = 0; i < 64; ++i) {
    float e = (-2.0f * (float)i) / 128.0f;
    th.t[i] = pfn(10000.0f, e);
  }

  // 2048 blocks x 4 waves = 8192 waves; 64-VGPR binary -> HW allows
  // 8 waves/SIMD, so all 8 blocks/CU are co-resident. 2 rows per wave.
  int blocks = (batch + 7) / 8;
  if (blocks > 2048) blocks = 2048;
  spike_rope_kernel<<<blocks, 256, 0, stream>>>(x, position, out, th, batch);
}